// Round 1
// baseline (123.958 us; speedup 1.0000x reference)
//
#include <hip/hip_runtime.h>

// 2-layer dense GAT, B=32, N=1024, fp32. L1: H=3,F=4,O=2 -> ws. L2: H=1,F=6,O=4 -> out.
//
// Round-10: algorithmic rewrite. LeakyReLU(e) is piecewise-linear in
// s_src[n]+s_dst[m], so per row the (scale-cancelled) softmax weight is
//   w(n,m) = rho(n)*E1(m)  if s_dst[m] > -s_src[n]   (rho=e^{0.8 s_src}, E1=e^{s_dst})
//          = E2(m)         otherwise                  (E2=e^{0.2 s_dst})
// => den/num are threshold-split sums of row-independent m-side quantities.
// Bucket s_dst into NB=512 bins, accumulate per-bucket {E1, E1*Wh_o, E2, E2*Wh_o}
// (LDS float atomics), one prefix + one suffix scan over buckets, and each row is
// O(1) + an exact max(rho*E1,E2) sweep over its single boundary bucket (elements
// bucket-sorted via rank-scatter). O(N) per (b,h) instead of O(N^2).
// Quantizer monotonicity guarantees: bucket>bq => key>theta (positive branch
// exact), bucket<bq => key<theta (negative exact); boundary bucket uses the
// max-form which is exact for ANY element, so the partition is exact.

#define GAT_ALPHA 0.2f
#define LOG2E 1.44269504088896f

__device__ __forceinline__ float ex2(float v) { return __builtin_amdgcn_exp2f(v); }

template <int F, int O, int H, int RPB>
__global__ __launch_bounds__(256) void gat_bucket_kernel(
    const float* __restrict__ x,            // (B, N, F)
    const float* __restrict__ Wt,           // (H, F, O)
    const float* __restrict__ at,           // (H, 2*O)
    float* __restrict__ out)                // (B, N, H*O)
{
    constexpr int N = 1024, NT = 256, EPT = N / NT;   // 4 elements/thread
    constexpr int NB = 512;                           // buckets (2 per thread)
    constexpr int CHUNKS = N / RPB;
    constexpr int A1 = O + 1;                         // den + O numerators

    const int bid   = blockIdx.x;
    const int chunk = bid % CHUNKS;
    const int h     = (bid / CHUNKS) % H;
    const int b     = bid / (CHUNKS * H);
    const int tid   = threadIdx.x;
    const int wv    = tid >> 6, ln = tid & 63;

    // Per-head weights (block-uniform -> scalar loads)
    float Wl[F][O], asrc[O], adst[O];
#pragma unroll
    for (int f = 0; f < F; ++f)
#pragma unroll
        for (int o = 0; o < O; ++o) Wl[f][o] = Wt[(h * F + f) * O + o];
#pragma unroll
    for (int o = 0; o < O; ++o) {
        asrc[o] = at[h * 2 * O + o];
        adst[o] = at[h * 2 * O + O + o];
    }

    __shared__ float sSrc[N];               // s_src per element (rows need it)
    __shared__ int   sCS[NB + 1];           // counts -> exclusive starts (in place)
    __shared__ float sKey[N];               // bucket-sorted s_dst
    __shared__ float sWhS[O][N];            // bucket-sorted Wh
    __shared__ float sPre[A1][NB + 1];      // E2-family: raw bucket sums -> prefix-excl
    __shared__ float sSuf[A1][NB + 1];      // E1-family: raw bucket sums -> suffix-incl
    __shared__ float sMM[8];
    __shared__ int   sRedI[4];
    __shared__ float sRedF[2][A1][4];

    // zero counters / accumulators
    for (int i = tid; i < NB + 1; i += NT) sCS[i] = 0;
    for (int i = tid; i < A1 * (NB + 1); i += NT) {
        (&sPre[0][0])[i] = 0.0f;
        (&sSuf[0][0])[i] = 0.0f;
    }

    // ---- Phase 1: per-element Wh, key=s_dst, s_src; block min/max of key ----
    float key[EPT], wh[EPT][O];
    float kmin = 3.4e38f, kmax = -3.4e38f;
    const float* xb = x + (size_t)b * N * F;
#pragma unroll
    for (int k = 0; k < EPT; ++k) {
        const int m = k * NT + tid;
        float xv[F];
        if constexpr (F == 4) {
            const float4 v = ((const float4*)xb)[m];
            xv[0] = v.x; xv[1] = v.y; xv[2] = v.z; xv[3] = v.w;
        } else {  // F == 6: 24B row = 3x float2 (8B-aligned)
            const float2* x2 = (const float2*)xb;
            const float2 va = x2[3 * m], vb = x2[3 * m + 1], vc = x2[3 * m + 2];
            xv[0] = va.x; xv[1] = va.y; xv[2] = vb.x;
            xv[3] = vb.y; xv[4] = vc.x; xv[5] = vc.y;
        }
        float d = 0.0f, sn = 0.0f;
#pragma unroll
        for (int o = 0; o < O; ++o) {
            float acc = 0.0f;
#pragma unroll
            for (int f = 0; f < F; ++f) acc += xv[f] * Wl[f][o];
            wh[k][o] = acc;
            d += acc * adst[o];
            sn += acc * asrc[o];
        }
        key[k] = d;
        sSrc[m] = sn;
        kmin = fminf(kmin, d);
        kmax = fmaxf(kmax, d);
    }
#pragma unroll
    for (int s = 1; s < 64; s <<= 1) {
        kmin = fminf(kmin, __shfl_xor(kmin, s, 64));
        kmax = fmaxf(kmax, __shfl_xor(kmax, s, 64));
    }
    if (ln == 0) { sMM[wv] = kmin; sMM[4 + wv] = kmax; }
    __syncthreads();  // zeros + sSrc + sMM done

    kmin = fminf(fminf(sMM[0], sMM[1]), fminf(sMM[2], sMM[3]));
    kmax = fmaxf(fmaxf(sMM[4], sMM[5]), fmaxf(sMM[6], sMM[7]));
    const float invw = (float)NB / fmaxf(kmax - kmin, 1e-30f);  // guard degenerate range

    // ---- Phase 2: bucket + rank + per-bucket sum accumulation (LDS atomics) ----
    int bk[EPT], rk[EPT];
#pragma unroll
    for (int k = 0; k < EPT; ++k) {
        int q = (int)((key[k] - kmin) * invw);
        q = q < 0 ? 0 : (q > NB - 1 ? NB - 1 : q);
        bk[k] = q;
        rk[k] = atomicAdd(&sCS[q], 1);
        const float e1 = ex2(LOG2E * key[k]);
        const float e2 = ex2(GAT_ALPHA * LOG2E * key[k]);
        atomicAdd(&sSuf[0][q], e1);
        atomicAdd(&sPre[0][q], e2);
#pragma unroll
        for (int o = 0; o < O; ++o) {
            atomicAdd(&sSuf[1 + o][q], e1 * wh[k][o]);
            atomicAdd(&sPre[1 + o][q], e2 * wh[k][o]);
        }
    }
    __syncthreads();  // counts + raw bucket sums complete

    // ---- Phase 3: combined in-place scans. Thread owns buckets 2t, 2t+1. ----
    // int counts -> exclusive starts; sPre -> prefix-exclusive; sSuf -> suffix-
    // inclusive. Cross-wave via tiny scratch; additions only (no cancellation).
    const int c0 = sCS[2 * tid], c1 = sCS[2 * tid + 1];
    float p0[A1], p1[A1], s0[A1], s1[A1];
#pragma unroll
    for (int a = 0; a < A1; ++a) {
        p0[a] = sPre[a][2 * tid]; p1[a] = sPre[a][2 * tid + 1];
        s0[a] = sSuf[a][2 * tid]; s1[a] = sSuf[a][2 * tid + 1];
    }
    int irun = c0 + c1;
#pragma unroll
    for (int s = 1; s < 64; s <<= 1) {
        const int u = __shfl_up(irun, s, 64);
        if (ln >= s) irun += u;
    }
    if (ln == 63) sRedI[wv] = irun;
    int irex = __shfl_up(irun, 1, 64);
    if (ln == 0) irex = 0;

    float prun[A1], prex[A1], srun[A1], srex[A1];
#pragma unroll
    for (int a = 0; a < A1; ++a) {
        prun[a] = p0[a] + p1[a];
#pragma unroll
        for (int s = 1; s < 64; s <<= 1) {
            const float u = __shfl_up(prun[a], s, 64);
            if (ln >= s) prun[a] += u;
        }
        if (ln == 63) sRedF[0][a][wv] = prun[a];
        prex[a] = __shfl_up(prun[a], 1, 64);
        if (ln == 0) prex[a] = 0.0f;

        srun[a] = s0[a] + s1[a];
#pragma unroll
        for (int s = 1; s < 64; s <<= 1) {
            const float u = __shfl_down(srun[a], s, 64);
            if (ln < 64 - s) srun[a] += u;
        }
        if (ln == 0) sRedF[1][a][wv] = srun[a];
        srex[a] = __shfl_down(srun[a], 1, 64);
        if (ln == 63) srex[a] = 0.0f;
    }
    __syncthreads();  // scratch written

    {
        int ibase = 0;
        for (int w = 0; w < 4; ++w) if (w < wv) ibase += sRedI[w];
        const int iex = ibase + irex;
        sCS[2 * tid] = iex;
        sCS[2 * tid + 1] = iex + c0;
        if (tid == 0) sCS[NB] = N;
    }
#pragma unroll
    for (int a = 0; a < A1; ++a) {
        float pbase = 0.0f, sbase = 0.0f;
        for (int w = 0; w < 4; ++w) {
            if (w < wv) pbase += sRedF[0][a][w];
            if (w > wv) sbase += sRedF[1][a][w];
        }
        const float pex = pbase + prex[a];      // sum over buckets < 2t
        sPre[a][2 * tid] = pex;
        sPre[a][2 * tid + 1] = pex + p0[a];
        const float sex = sbase + srex[a];      // sum over buckets > 2t+1
        sSuf[a][2 * tid + 1] = sex + s1[a];
        sSuf[a][2 * tid] = sex + s1[a] + s0[a];
        // sSuf[a][NB] stays 0 from init
    }
    __syncthreads();  // starts + scans ready

    // ---- Phase 4: scatter elements into bucket-sorted order ----
#pragma unroll
    for (int k = 0; k < EPT; ++k) {
        const int pos = sCS[bk[k]] + rk[k];
        sKey[pos] = key[k];
#pragma unroll
        for (int o = 0; o < O; ++o) sWhS[o][pos] = wh[k][o];
    }
    __syncthreads();  // sorted arrays ready

    // ---- Phase 5: per-row O(1) combine + exact boundary-bucket sweep ----
    for (int rr = tid; rr < RPB; rr += NT) {
        const int row = chunk * RPB + rr;
        const float sn = sSrc[row];
        const float rho = ex2(0.8f * LOG2E * sn);
        int bq = (int)((-sn - kmin) * invw);
        bq = bq < 0 ? 0 : (bq > NB - 1 ? NB - 1 : bq);
        const int i0 = sCS[bq], i1 = sCS[bq + 1];
        float den = rho * sSuf[0][bq + 1] + sPre[0][bq];
        float num[O];
#pragma unroll
        for (int o = 0; o < O; ++o)
            num[o] = rho * sSuf[1 + o][bq + 1] + sPre[1 + o][bq];
        for (int i = i0; i < i1; ++i) {         // boundary bucket: exact max-form
            const float kk = sKey[i];
            const float w = fmaxf(rho * ex2(LOG2E * kk), ex2(GAT_ALPHA * LOG2E * kk));
            den += w;
#pragma unroll
            for (int o = 0; o < O; ++o) num[o] += w * sWhS[o][i];
        }
#pragma unroll
        for (int o = 0; o < O; ++o) {
            float v = num[o] / den;                        // scale cancels; den > 0
            v = (v > 0.0f) ? v : (__expf(v) - 1.0f);       // ELU(alpha=1)
            out[((size_t)b * N + row) * (H * O) + h * O + o] = v;
        }
    }
}

extern "C" void kernel_launch(void* const* d_in, const int* in_sizes, int n_in,
                              void* d_out, int out_size, void* d_ws, size_t ws_size,
                              hipStream_t stream) {
    const float* x  = (const float*)d_in[0];  // (32,1024,4)
    const float* W1 = (const float*)d_in[1];  // (3,4,2)
    const float* a1 = (const float*)d_in[2];  // (3,4,1)
    const float* W2 = (const float*)d_in[3];  // (1,6,4)
    const float* a2 = (const float*)d_in[4];  // (1,8,1)

    float* h1 = (float*)d_ws;     // (32,1024,6) fp32 = 768 KiB scratch
    float* y  = (float*)d_out;    // (32,1024,4) fp32

    constexpr int B = 32;
    // Layer 1: H=3,F=4,O=2, RPB=128 -> 768 blocks (3/CU, LDS ~31 KB)
    gat_bucket_kernel<4, 2, 3, 128><<<B * 3 * (1024 / 128), 256, 0, stream>>>(x, W1, a1, h1);
    // Layer 2: H=1,F=6,O=4, RPB=64 -> 512 blocks (2/CU, LDS ~47 KB)
    gat_bucket_kernel<6, 4, 1, 64><<<B * 1 * (1024 / 64), 256, 0, stream>>>(h1, W2, a2, y);
}

// Round 2
// 97.398 us; speedup vs baseline: 1.2727x; 1.2727x over previous
//
#include <hip/hip_runtime.h>

// 2-layer dense GAT, B=32, N=1024, fp32. L1: H=3,F=4,O=2 -> ws. L2: H=1,F=6,O=4 -> out.
//
// Round-11: bucket algorithm (round-10, verified correct) with CHUNKS=1.
// One block per (b,h): stage + bucket + scan + scatter ONCE, then all N rows.
// Round-10 ran the O(N) staging redundantly 8-16x across chunk-blocks (1.4M
// wave-inst for L1); this version is 0.23M wave-inst (6x less) and is bound by
// the per-block critical path (~600 inst + 5 barriers), with 96/32 blocks.
//
// Algorithm: LeakyReLU(e) is piecewise-linear in s_src[n]+s_dst[m], so per row
//   w(n,m) = rho(n)*E1(m)  if s_dst[m] > -s_src[n]   (rho=e^{0.8 s_src}, E1=e^{s_dst})
//          = E2(m)         otherwise                  (E2=e^{0.2 s_dst})
// Bucket s_dst into NB=512 bins, per-bucket sums {E1,E1*Wh_o} / {E2,E2*Wh_o},
// prefix(E2-family) + suffix(E1-family) scans, each row = O(1) lookup + exact
// max(rho*E1,E2) sweep over its single boundary bucket (elements bucket-sorted
// by rank-scatter). Monotone quantizer => partition exact; boundary max-form is
// exact for any element, so no misclassification is possible.

#define GAT_ALPHA 0.2f
#define LOG2E 1.44269504088896f

__device__ __forceinline__ float ex2(float v) { return __builtin_amdgcn_exp2f(v); }

template <int F, int O, int H>
__global__ __launch_bounds__(256) void gat_bucket_kernel(
    const float* __restrict__ x,            // (B, N, F)
    const float* __restrict__ Wt,           // (H, F, O)
    const float* __restrict__ at,           // (H, 2*O)
    float* __restrict__ out)                // (B, N, H*O)
{
    constexpr int N = 1024, NT = 256, EPT = N / NT;   // 4 elements/thread
    constexpr int NB = 512;                           // buckets (2 per thread)
    constexpr int A1 = O + 1;                         // den + O numerators

    const int bid   = blockIdx.x;
    const int h     = bid % H;
    const int b     = bid / H;
    const int tid   = threadIdx.x;
    const int wv    = tid >> 6, ln = tid & 63;

    // Per-head weights (block-uniform -> scalar loads)
    float Wl[F][O], asrc[O], adst[O];
#pragma unroll
    for (int f = 0; f < F; ++f)
#pragma unroll
        for (int o = 0; o < O; ++o) Wl[f][o] = Wt[(h * F + f) * O + o];
#pragma unroll
    for (int o = 0; o < O; ++o) {
        asrc[o] = at[h * 2 * O + o];
        adst[o] = at[h * 2 * O + O + o];
    }

    __shared__ float sSrc[N];               // s_src per element (rows need it)
    __shared__ int   sCS[NB + 1];           // counts -> exclusive starts (in place)
    __shared__ float sKey[N];               // bucket-sorted s_dst
    __shared__ float sWhS[O][N];            // bucket-sorted Wh
    __shared__ float sPre[A1][NB + 1];      // E2-family: raw bucket sums -> prefix-excl
    __shared__ float sSuf[A1][NB + 1];      // E1-family: raw bucket sums -> suffix-incl
    __shared__ float sMM[8];
    __shared__ int   sRedI[4];
    __shared__ float sRedF[2][A1][4];

    // zero counters / accumulators
    for (int i = tid; i < NB + 1; i += NT) sCS[i] = 0;
    for (int i = tid; i < A1 * (NB + 1); i += NT) {
        (&sPre[0][0])[i] = 0.0f;
        (&sSuf[0][0])[i] = 0.0f;
    }

    // ---- Phase 1: per-element Wh, key=s_dst, s_src; block min/max of key ----
    float key[EPT], wh[EPT][O];
    float kmin = 3.4e38f, kmax = -3.4e38f;
    const float* xb = x + (size_t)b * N * F;
#pragma unroll
    for (int k = 0; k < EPT; ++k) {
        const int m = k * NT + tid;
        float xv[F];
        if constexpr (F == 4) {
            const float4 v = ((const float4*)xb)[m];
            xv[0] = v.x; xv[1] = v.y; xv[2] = v.z; xv[3] = v.w;
        } else {  // F == 6: 24B row = 3x float2 (8B-aligned)
            const float2* x2 = (const float2*)xb;
            const float2 va = x2[3 * m], vb = x2[3 * m + 1], vc = x2[3 * m + 2];
            xv[0] = va.x; xv[1] = va.y; xv[2] = vb.x;
            xv[3] = vb.y; xv[4] = vc.x; xv[5] = vc.y;
        }
        float d = 0.0f, sn = 0.0f;
#pragma unroll
        for (int o = 0; o < O; ++o) {
            float acc = 0.0f;
#pragma unroll
            for (int f = 0; f < F; ++f) acc += xv[f] * Wl[f][o];
            wh[k][o] = acc;
            d += acc * adst[o];
            sn += acc * asrc[o];
        }
        key[k] = d;
        sSrc[m] = sn;
        kmin = fminf(kmin, d);
        kmax = fmaxf(kmax, d);
    }
#pragma unroll
    for (int s = 1; s < 64; s <<= 1) {
        kmin = fminf(kmin, __shfl_xor(kmin, s, 64));
        kmax = fmaxf(kmax, __shfl_xor(kmax, s, 64));
    }
    if (ln == 0) { sMM[wv] = kmin; sMM[4 + wv] = kmax; }
    __syncthreads();  // zeros + sSrc + sMM done

    kmin = fminf(fminf(sMM[0], sMM[1]), fminf(sMM[2], sMM[3]));
    kmax = fmaxf(fmaxf(sMM[4], sMM[5]), fmaxf(sMM[6], sMM[7]));
    const float invw = (float)NB / fmaxf(kmax - kmin, 1e-30f);  // guard degenerate range

    // ---- Phase 2: bucket + rank + per-bucket sum accumulation (LDS atomics) ----
    int bk[EPT], rk[EPT];
#pragma unroll
    for (int k = 0; k < EPT; ++k) {
        int q = (int)((key[k] - kmin) * invw);
        q = q < 0 ? 0 : (q > NB - 1 ? NB - 1 : q);
        bk[k] = q;
        rk[k] = atomicAdd(&sCS[q], 1);
        const float e1 = ex2(LOG2E * key[k]);
        const float e2 = ex2(GAT_ALPHA * LOG2E * key[k]);
        atomicAdd(&sSuf[0][q], e1);
        atomicAdd(&sPre[0][q], e2);
#pragma unroll
        for (int o = 0; o < O; ++o) {
            atomicAdd(&sSuf[1 + o][q], e1 * wh[k][o]);
            atomicAdd(&sPre[1 + o][q], e2 * wh[k][o]);
        }
    }
    __syncthreads();  // counts + raw bucket sums complete

    // ---- Phase 3: combined in-place scans. Thread owns buckets 2t, 2t+1. ----
    // int counts -> exclusive starts; sPre -> prefix-exclusive; sSuf -> suffix-
    // inclusive. Cross-wave via tiny scratch; additions only (no cancellation).
    const int c0 = sCS[2 * tid], c1 = sCS[2 * tid + 1];
    float p0[A1], p1[A1], s0[A1], s1[A1];
#pragma unroll
    for (int a = 0; a < A1; ++a) {
        p0[a] = sPre[a][2 * tid]; p1[a] = sPre[a][2 * tid + 1];
        s0[a] = sSuf[a][2 * tid]; s1[a] = sSuf[a][2 * tid + 1];
    }
    int irun = c0 + c1;
#pragma unroll
    for (int s = 1; s < 64; s <<= 1) {
        const int u = __shfl_up(irun, s, 64);
        if (ln >= s) irun += u;
    }
    if (ln == 63) sRedI[wv] = irun;
    int irex = __shfl_up(irun, 1, 64);
    if (ln == 0) irex = 0;

    float prun[A1], prex[A1], srun[A1], srex[A1];
#pragma unroll
    for (int a = 0; a < A1; ++a) {
        prun[a] = p0[a] + p1[a];
#pragma unroll
        for (int s = 1; s < 64; s <<= 1) {
            const float u = __shfl_up(prun[a], s, 64);
            if (ln >= s) prun[a] += u;
        }
        if (ln == 63) sRedF[0][a][wv] = prun[a];
        prex[a] = __shfl_up(prun[a], 1, 64);
        if (ln == 0) prex[a] = 0.0f;

        srun[a] = s0[a] + s1[a];
#pragma unroll
        for (int s = 1; s < 64; s <<= 1) {
            const float u = __shfl_down(srun[a], s, 64);
            if (ln < 64 - s) srun[a] += u;
        }
        if (ln == 0) sRedF[1][a][wv] = srun[a];
        srex[a] = __shfl_down(srun[a], 1, 64);
        if (ln == 63) srex[a] = 0.0f;
    }
    __syncthreads();  // scratch written

    {
        int ibase = 0;
        for (int w = 0; w < 4; ++w) if (w < wv) ibase += sRedI[w];
        const int iex = ibase + irex;
        sCS[2 * tid] = iex;
        sCS[2 * tid + 1] = iex + c0;
        if (tid == 0) sCS[NB] = N;
    }
#pragma unroll
    for (int a = 0; a < A1; ++a) {
        float pbase = 0.0f, sbase = 0.0f;
        for (int w = 0; w < 4; ++w) {
            if (w < wv) pbase += sRedF[0][a][w];
            if (w > wv) sbase += sRedF[1][a][w];
        }
        const float pex = pbase + prex[a];      // sum over buckets < 2t
        sPre[a][2 * tid] = pex;
        sPre[a][2 * tid + 1] = pex + p0[a];
        const float sex = sbase + srex[a];      // sum over buckets > 2t+1
        sSuf[a][2 * tid + 1] = sex + s1[a];
        sSuf[a][2 * tid] = sex + s1[a] + s0[a];
        // sSuf[a][NB] stays 0 from init
    }
    __syncthreads();  // starts + scans ready

    // ---- Phase 4: scatter elements into bucket-sorted order ----
#pragma unroll
    for (int k = 0; k < EPT; ++k) {
        const int pos = sCS[bk[k]] + rk[k];
        sKey[pos] = key[k];
#pragma unroll
        for (int o = 0; o < O; ++o) sWhS[o][pos] = wh[k][o];
    }
    __syncthreads();  // sorted arrays ready

    // ---- Phase 5: all N rows, 4 per thread: O(1) combine + boundary sweep ----
    for (int rr = tid; rr < N; rr += NT) {
        const int row = rr;
        const float sn = sSrc[row];
        const float rho = ex2(0.8f * LOG2E * sn);
        int bq = (int)((-sn - kmin) * invw);
        bq = bq < 0 ? 0 : (bq > NB - 1 ? NB - 1 : bq);
        const int i0 = sCS[bq], i1 = sCS[bq + 1];
        float den = rho * sSuf[0][bq + 1] + sPre[0][bq];
        float num[O];
#pragma unroll
        for (int o = 0; o < O; ++o)
            num[o] = rho * sSuf[1 + o][bq + 1] + sPre[1 + o][bq];
        for (int i = i0; i < i1; ++i) {         // boundary bucket: exact max-form
            const float kk = sKey[i];
            const float w = fmaxf(rho * ex2(LOG2E * kk), ex2(GAT_ALPHA * LOG2E * kk));
            den += w;
#pragma unroll
            for (int o = 0; o < O; ++o) num[o] += w * sWhS[o][i];
        }
#pragma unroll
        for (int o = 0; o < O; ++o) {
            float v = num[o] / den;                        // scale cancels; den > 0
            v = (v > 0.0f) ? v : (__expf(v) - 1.0f);       // ELU(alpha=1)
            out[((size_t)b * N + row) * (H * O) + h * O + o] = v;
        }
    }
}

extern "C" void kernel_launch(void* const* d_in, const int* in_sizes, int n_in,
                              void* d_out, int out_size, void* d_ws, size_t ws_size,
                              hipStream_t stream) {
    const float* x  = (const float*)d_in[0];  // (32,1024,4)
    const float* W1 = (const float*)d_in[1];  // (3,4,2)
    const float* a1 = (const float*)d_in[2];  // (3,4,1)
    const float* W2 = (const float*)d_in[3];  // (1,6,4)
    const float* a2 = (const float*)d_in[4];  // (1,8,1)

    float* h1 = (float*)d_ws;     // (32,1024,6) fp32 = 768 KiB scratch
    float* y  = (float*)d_out;    // (32,1024,4) fp32

    constexpr int B = 32;
    // Layer 1: H=3,F=4,O=2 -> 96 blocks, one per (b,h), LDS ~31 KB
    gat_bucket_kernel<4, 2, 3><<<B * 3, 256, 0, stream>>>(x, W1, a1, h1);
    // Layer 2: H=1,F=6,O=4 -> 32 blocks, one per (b,h), LDS ~47 KB
    gat_bucket_kernel<6, 4, 1><<<B * 1, 256, 0, stream>>>(h1, W2, a2, y);
}

// Round 3
// 91.511 us; speedup vs baseline: 1.3546x; 1.0643x over previous
//
#include <hip/hip_runtime.h>

// 2-layer dense GAT, B=32, N=1024, fp32. L1: H=3,F=4,O=2 -> ws. L2: H=1,F=6,O=4 -> out.
//
// Round-12: same verified bucket algorithm as round-11, rescheduled for the
// latency-bound regime (96/32 blocks => ~1 block/CU). Changes:
//  * NT=1024 (16 waves/block): phases 1,2,4,5 do ONE item/thread (was 4) ->
//    per-thread serial depth /4, 4 waves/SIMD hide each other's latencies.
//  * Phase 3: each of the 2*A1+1 independent scans (int starts, A1 prefix,
//    A1 suffix) is done by ONE WAVE (8 buckets/lane: local scan + 6 shfl
//    steps, no internal barrier). 16 waves >= 11 jobs -> all concurrent.
//  * Still 4 barriers; math identical to the verified kernel.
//
// Algorithm: LeakyReLU(e) is piecewise-linear in s_src[n]+s_dst[m], so per row
//   w(n,m) = rho(n)*E1(m)  if s_dst[m] > -s_src[n]   (rho=e^{0.8 s_src}, E1=e^{s_dst})
//          = E2(m)         otherwise                  (E2=e^{0.2 s_dst})
// Bucket s_dst into NB=512 bins, per-bucket sums {E1,E1*Wh_o} / {E2,E2*Wh_o},
// prefix(E2) + suffix(E1) scans, each row = O(1) lookup + exact
// max(rho*E1,E2) sweep over its boundary bucket (elements rank-scattered into
// bucket-sorted order). Monotone quantizer => partition exact; boundary
// max-form is exact for any element.

#define GAT_ALPHA 0.2f
#define LOG2E 1.44269504088896f

__device__ __forceinline__ float ex2(float v) { return __builtin_amdgcn_exp2f(v); }

template <int F, int O, int H, int NT>
__global__ __launch_bounds__(NT) void gat_bucket_kernel(
    const float* __restrict__ x,            // (B, N, F)
    const float* __restrict__ Wt,           // (H, F, O)
    const float* __restrict__ at,           // (H, 2*O)
    float* __restrict__ out)                // (B, N, H*O)
{
    constexpr int N = 1024, EPT = N / NT;             // 1 element/thread at NT=1024
    constexpr int NB = 512;                           // buckets
    constexpr int A1 = O + 1;                         // den + O numerators
    constexpr int NW = NT / 64;                       // waves (16)
    constexpr int NJOBS = 2 * A1 + 1;                 // scan jobs (7 or 11)
    constexpr int BPL = NB / 64;                      // buckets per lane (8)

    const int bid = blockIdx.x;
    const int h   = bid % H;
    const int b   = bid / H;
    const int tid = threadIdx.x;
    const int wv  = tid >> 6, ln = tid & 63;

    // Per-head weights (block-uniform -> scalar loads)
    float Wl[F][O], asrc[O], adst[O];
#pragma unroll
    for (int f = 0; f < F; ++f)
#pragma unroll
        for (int o = 0; o < O; ++o) Wl[f][o] = Wt[(h * F + f) * O + o];
#pragma unroll
    for (int o = 0; o < O; ++o) {
        asrc[o] = at[h * 2 * O + o];
        adst[o] = at[h * 2 * O + O + o];
    }

    __shared__ float sSrc[N];               // s_src per element
    __shared__ int   sCS[NB + 1];           // counts -> exclusive starts (in place)
    __shared__ float sKey[N];               // bucket-sorted s_dst
    __shared__ float sWhS[O][N];            // bucket-sorted Wh
    __shared__ float sPre[A1][NB + 1];      // E2-family: bucket sums -> prefix-excl
    __shared__ float sSuf[A1][NB + 1];      // E1-family: bucket sums -> suffix-incl
    __shared__ float sMM[2 * NW];

    // zero counters / accumulators
    for (int i = tid; i < NB + 1; i += NT) sCS[i] = 0;
    for (int i = tid; i < A1 * (NB + 1); i += NT) {
        (&sPre[0][0])[i] = 0.0f;
        (&sSuf[0][0])[i] = 0.0f;
    }

    // ---- Phase 1: per-element Wh, key=s_dst, s_src; block min/max of key ----
    float key[EPT], wh[EPT][O];
    float kmin = 3.4e38f, kmax = -3.4e38f;
    const float* xb = x + (size_t)b * N * F;
#pragma unroll
    for (int k = 0; k < EPT; ++k) {
        const int m = k * NT + tid;
        float xv[F];
        if constexpr (F == 4) {
            const float4 v = ((const float4*)xb)[m];
            xv[0] = v.x; xv[1] = v.y; xv[2] = v.z; xv[3] = v.w;
        } else {  // F == 6: 24B row = 3x float2 (8B-aligned)
            const float2* x2 = (const float2*)xb;
            const float2 va = x2[3 * m], vb = x2[3 * m + 1], vc = x2[3 * m + 2];
            xv[0] = va.x; xv[1] = va.y; xv[2] = vb.x;
            xv[3] = vb.y; xv[4] = vc.x; xv[5] = vc.y;
        }
        float d = 0.0f, sn = 0.0f;
#pragma unroll
        for (int o = 0; o < O; ++o) {
            float acc = 0.0f;
#pragma unroll
            for (int f = 0; f < F; ++f) acc += xv[f] * Wl[f][o];
            wh[k][o] = acc;
            d += acc * adst[o];
            sn += acc * asrc[o];
        }
        key[k] = d;
        sSrc[m] = sn;
        kmin = fminf(kmin, d);
        kmax = fmaxf(kmax, d);
    }
#pragma unroll
    for (int s = 1; s < 64; s <<= 1) {
        kmin = fminf(kmin, __shfl_xor(kmin, s, 64));
        kmax = fmaxf(kmax, __shfl_xor(kmax, s, 64));
    }
    if (ln == 0) { sMM[wv] = kmin; sMM[NW + wv] = kmax; }
    __syncthreads();  // zeros + sSrc + sMM done

    kmin = sMM[0]; kmax = sMM[NW];
#pragma unroll
    for (int w = 1; w < NW; ++w) {
        kmin = fminf(kmin, sMM[w]);
        kmax = fmaxf(kmax, sMM[NW + w]);
    }
    const float invw = (float)NB / fmaxf(kmax - kmin, 1e-30f);  // guard degenerate range

    // ---- Phase 2: bucket + rank + per-bucket sum accumulation (LDS atomics) ----
    int bk[EPT], rk[EPT];
#pragma unroll
    for (int k = 0; k < EPT; ++k) {
        int q = (int)((key[k] - kmin) * invw);
        q = q < 0 ? 0 : (q > NB - 1 ? NB - 1 : q);
        bk[k] = q;
        rk[k] = atomicAdd(&sCS[q], 1);
        const float e1 = ex2(LOG2E * key[k]);
        const float e2 = ex2(GAT_ALPHA * LOG2E * key[k]);
        atomicAdd(&sSuf[0][q], e1);
        atomicAdd(&sPre[0][q], e2);
#pragma unroll
        for (int o = 0; o < O; ++o) {
            atomicAdd(&sSuf[1 + o][q], e1 * wh[k][o]);
            atomicAdd(&sPre[1 + o][q], e2 * wh[k][o]);
        }
    }
    __syncthreads();  // counts + raw bucket sums complete

    // ---- Phase 3: one WAVE per scan job, 8 buckets/lane, no internal barrier.
    // job 0: int counts -> exclusive starts; jobs 1..A1: sPre[a] prefix-excl;
    // jobs A1+1..2A1: sSuf[a] suffix-incl.
    if (wv < NJOBS) {
        if (wv == 0) {
            int c[BPL];
#pragma unroll
            for (int i = 0; i < BPL; ++i) c[i] = sCS[ln * BPL + i];
            int s = 0;
#pragma unroll
            for (int i = 0; i < BPL; ++i) s += c[i];
            int run = s;
#pragma unroll
            for (int d = 1; d < 64; d <<= 1) {
                const int u = __shfl_up(run, d, 64);
                if (ln >= d) run += u;
            }
            int acc = run - s;                   // exclusive base for this lane
#pragma unroll
            for (int i = 0; i < BPL; ++i) {
                const int t = acc; acc += c[i];
                sCS[ln * BPL + i] = t;
            }
            if (ln == 0) sCS[NB] = N;            // total is always N
        } else if (wv <= A1) {
            float* arr = &sPre[wv - 1][0];
            float v[BPL];
#pragma unroll
            for (int i = 0; i < BPL; ++i) v[i] = arr[ln * BPL + i];
            float s = 0.0f;
#pragma unroll
            for (int i = 0; i < BPL; ++i) s += v[i];
            float run = s;
#pragma unroll
            for (int d = 1; d < 64; d <<= 1) {
                const float u = __shfl_up(run, d, 64);
                if (ln >= d) run += u;
            }
            float acc = run - s;                 // sum over lanes < ln
#pragma unroll
            for (int i = 0; i < BPL; ++i) {
                const float t = acc; acc += v[i];
                arr[ln * BPL + i] = t;           // exclusive prefix
            }
        } else {
            float* arr = &sSuf[wv - A1 - 1][0];
            float v[BPL];
#pragma unroll
            for (int i = 0; i < BPL; ++i) v[i] = arr[ln * BPL + i];
            float s = 0.0f;
#pragma unroll
            for (int i = 0; i < BPL; ++i) s += v[i];
            float run = s;
#pragma unroll
            for (int d = 1; d < 64; d <<= 1) {
                const float u = __shfl_down(run, d, 64);
                if (ln < 64 - d) run += u;
            }
            float acc = run - s;                 // sum over lanes > ln
#pragma unroll
            for (int i = BPL - 1; i >= 0; --i) {
                acc += v[i];
                arr[ln * BPL + i] = acc;         // suffix inclusive
            }
            // arr[NB] stays 0 from init
        }
    }
    __syncthreads();  // starts + scans ready

    // ---- Phase 4: scatter elements into bucket-sorted order ----
#pragma unroll
    for (int k = 0; k < EPT; ++k) {
        const int pos = sCS[bk[k]] + rk[k];
        sKey[pos] = key[k];
#pragma unroll
        for (int o = 0; o < O; ++o) sWhS[o][pos] = wh[k][o];
    }
    __syncthreads();  // sorted arrays ready

    // ---- Phase 5: one row/thread: O(1) combine + exact boundary sweep ----
    for (int rr = tid; rr < N; rr += NT) {
        const float sn = sSrc[rr];
        const float rho = ex2(0.8f * LOG2E * sn);
        int bq = (int)((-sn - kmin) * invw);
        bq = bq < 0 ? 0 : (bq > NB - 1 ? NB - 1 : bq);
        const int i0 = sCS[bq], i1 = sCS[bq + 1];
        float den = rho * sSuf[0][bq + 1] + sPre[0][bq];
        float num[O];
#pragma unroll
        for (int o = 0; o < O; ++o)
            num[o] = rho * sSuf[1 + o][bq + 1] + sPre[1 + o][bq];
        for (int i = i0; i < i1; ++i) {         // boundary bucket: exact max-form
            const float kk = sKey[i];
            const float w = fmaxf(rho * ex2(LOG2E * kk), ex2(GAT_ALPHA * LOG2E * kk));
            den += w;
#pragma unroll
            for (int o = 0; o < O; ++o) num[o] += w * sWhS[o][i];
        }
#pragma unroll
        for (int o = 0; o < O; ++o) {
            float v = num[o] / den;                        // scale cancels; den > 0
            v = (v > 0.0f) ? v : (__expf(v) - 1.0f);       // ELU(alpha=1)
            out[((size_t)b * N + rr) * (H * O) + h * O + o] = v;
        }
    }
}

extern "C" void kernel_launch(void* const* d_in, const int* in_sizes, int n_in,
                              void* d_out, int out_size, void* d_ws, size_t ws_size,
                              hipStream_t stream) {
    const float* x  = (const float*)d_in[0];  // (32,1024,4)
    const float* W1 = (const float*)d_in[1];  // (3,4,2)
    const float* a1 = (const float*)d_in[2];  // (3,4,1)
    const float* W2 = (const float*)d_in[3];  // (1,6,4)
    const float* a2 = (const float*)d_in[4];  // (1,8,1)

    float* h1 = (float*)d_ws;     // (32,1024,6) fp32 = 768 KiB scratch
    float* y  = (float*)d_out;    // (32,1024,4) fp32

    constexpr int B = 32;
    // Layer 1: H=3,F=4,O=2 -> 96 blocks x 1024 threads (16 waves), LDS ~31 KB
    gat_bucket_kernel<4, 2, 3, 1024><<<B * 3, 1024, 0, stream>>>(x, W1, a1, h1);
    // Layer 2: H=1,F=6,O=4 -> 32 blocks x 1024 threads (16 waves), LDS ~47 KB
    gat_bucket_kernel<6, 4, 1, 1024><<<B * 1, 1024, 0, stream>>>(h1, W2, a2, y);
}